// Round 3
// baseline (116.661 us; speedup 1.0000x reference)
//
#include <hip/hip_runtime.h>
#include <hip/hip_bf16.h>
#include <stdint.h>

#define N_NODES 100000
#define IN_DIM 256
#define OUT_DIM 128
#define DEG 16

typedef __bf16 bf16x8 __attribute__((ext_vector_type(8)));
typedef float f32x4 __attribute__((ext_vector_type(4)));

// ---------------- kernel A: Wt[j][k] = bf16(W[k][j]) ----------------
__global__ void prep_w_kernel(const float* __restrict__ W, __bf16* __restrict__ Wt) {
    const int j = blockIdx.x;   // 0..127 (output col)
    const int k = threadIdx.x;  // 0..255 (input dim)
    Wt[j * IN_DIM + k] = (__bf16)W[k * OUT_DIM + j];
}

// ---------------- kernel B: XP[m][n] = bf16( sum_k X[m][k] * W[k][n] ) ----------------
// No LDS, no barriers. One wave owns 32 rows x all 128 cols.
// A-frags: direct global f32 loads (2x float4 per mi), cvt to bf16 in-register.
// B-frags: direct global loads from Wt (64KB, L2-resident).
// 12 loads + 16 MFMA per k-step, 8 k-steps, fully unrolled.
__global__ __launch_bounds__(256) void gemm_kernel(const float* __restrict__ X,
                                                   const __bf16* __restrict__ Wt,
                                                   __bf16* __restrict__ XP) {
    const int t = threadIdx.x;
    const int lane = t & 63;
    const int wid = blockIdx.x * 4 + (t >> 6);
    const int m0 = wid * 32;
    if (m0 >= N_NODES) return;
    const int lr = lane & 15;   // A row / B col / D col within fragment
    const int lg = lane >> 4;   // k-subgroup / D row-group

    f32x4 acc[2][8] = {};

    const float*  a0p = X  + (size_t)(m0 + lr) * IN_DIM + lg * 8;
    const float*  a1p = a0p + (size_t)16 * IN_DIM;
    const __bf16* bp  = Wt + (size_t)lr * IN_DIM + lg * 8;

    #pragma unroll
    for (int ks = 0; ks < 8; ++ks) {
        const int ko = ks * 32;
        // issue all 12 loads first
        float4 av00 = *reinterpret_cast<const float4*>(a0p + ko);
        float4 av01 = *reinterpret_cast<const float4*>(a0p + ko + 4);
        float4 av10 = *reinterpret_cast<const float4*>(a1p + ko);
        float4 av11 = *reinterpret_cast<const float4*>(a1p + ko + 4);
        bf16x8 b[8];
        #pragma unroll
        for (int ni = 0; ni < 8; ++ni)
            b[ni] = *reinterpret_cast<const bf16x8*>(bp + (size_t)ni * 16 * IN_DIM + ko);

        bf16x8 a0, a1;
        a0[0] = (__bf16)av00.x; a0[1] = (__bf16)av00.y; a0[2] = (__bf16)av00.z; a0[3] = (__bf16)av00.w;
        a0[4] = (__bf16)av01.x; a0[5] = (__bf16)av01.y; a0[6] = (__bf16)av01.z; a0[7] = (__bf16)av01.w;
        a1[0] = (__bf16)av10.x; a1[1] = (__bf16)av10.y; a1[2] = (__bf16)av10.z; a1[3] = (__bf16)av10.w;
        a1[4] = (__bf16)av11.x; a1[5] = (__bf16)av11.y; a1[6] = (__bf16)av11.z; a1[7] = (__bf16)av11.w;

        #pragma unroll
        for (int ni = 0; ni < 8; ++ni) {
            acc[0][ni] = __builtin_amdgcn_mfma_f32_16x16x32_bf16(a0, b[ni], acc[0][ni], 0, 0, 0);
            acc[1][ni] = __builtin_amdgcn_mfma_f32_16x16x32_bf16(a1, b[ni], acc[1][ni], 0, 0, 0);
        }
    }

    // C/D layout: col = lane&15, row = (lane>>4)*4 + r
    #pragma unroll
    for (int mi = 0; mi < 2; ++mi)
        #pragma unroll
        for (int ni = 0; ni < 8; ++ni)
            #pragma unroll
            for (int r = 0; r < 4; ++r) {
                const int row = m0 + mi * 16 + lg * 4 + r;
                const int col = ni * 16 + lr;
                XP[(size_t)row * OUT_DIM + col] = (__bf16)acc[mi][ni][r];
            }
}

// ---------------- kernel C: fused SDDMM + attention-weighted SpMM ----------------
// One wave per row. 4 groups of 16 lanes; group g owns edges [g*4, g*4+4);
// lane sl=lane&15 covers cols [sl*8, sl*8+8).
__global__ __launch_bounds__(256) void gat_edge_kernel(const __bf16* __restrict__ XP,
                                                       const int* __restrict__ rp,
                                                       const int* __restrict__ ci,
                                                       const float* __restrict__ attw,
                                                       float* __restrict__ out) {
    const int lane = threadIdx.x & 63;
    const int row = blockIdx.x * 4 + (threadIdx.x >> 6);
    const int g = lane >> 4;    // group 0..3
    const int sl = lane & 15;   // sub-lane: cols sl*8..sl*8+8

    float s = 0.f;
    #pragma unroll
    for (int h = 0; h < 8; ++h) s += attw[h];

    float x[8];
    {
        uint4 xv = *reinterpret_cast<const uint4*>(XP + (size_t)row * OUT_DIM + sl * 8);
        const uint32_t* xw = reinterpret_cast<const uint32_t*>(&xv);
        #pragma unroll
        for (int i = 0; i < 4; ++i) {
            x[2 * i]     = __uint_as_float(xw[i] << 16);
            x[2 * i + 1] = __uint_as_float(xw[i] & 0xffff0000u);
        }
    }

    const int4 cv = reinterpret_cast<const int4*>(ci + (size_t)row * DEG)[g];
    const int c[4] = {cv.x, cv.y, cv.z, cv.w};

    uint4 dvu[4];
    #pragma unroll
    for (int j = 0; j < 4; ++j)
        dvu[j] = *reinterpret_cast<const uint4*>(XP + (size_t)c[j] * OUT_DIM + sl * 8);

    float d[4][8];
    #pragma unroll
    for (int j = 0; j < 4; ++j) {
        const uint32_t* dw = reinterpret_cast<const uint32_t*>(&dvu[j]);
        #pragma unroll
        for (int i = 0; i < 4; ++i) {
            d[j][2 * i]     = __uint_as_float(dw[i] << 16);
            d[j][2 * i + 1] = __uint_as_float(dw[i] & 0xffff0000u);
        }
    }

    float p[4];
    #pragma unroll
    for (int j = 0; j < 4; ++j) {
        float t0 = 0.f;
        #pragma unroll
        for (int i = 0; i < 8; ++i) t0 += x[i] * d[j][i];
        p[j] = t0;
    }
    #pragma unroll
    for (int off = 1; off <= 8; off <<= 1) {
        #pragma unroll
        for (int j = 0; j < 4; ++j) p[j] += __shfl_xor(p[j], off);
    }

    float acc[8] = {};
    #pragma unroll
    for (int j = 0; j < 4; ++j) {
        const float att = p[j] * s;
        #pragma unroll
        for (int i = 0; i < 8; ++i) acc[i] += att * d[j][i];
    }

    #pragma unroll
    for (int off = 16; off <= 32; off <<= 1) {
        #pragma unroll
        for (int i = 0; i < 8; ++i) acc[i] += __shfl_xor(acc[i], off);
    }

    if (g == 0) {
        float4 o0, o1;
        o0.x = acc[0]; o0.y = acc[1]; o0.z = acc[2]; o0.w = acc[3];
        o1.x = acc[4]; o1.y = acc[5]; o1.z = acc[6]; o1.w = acc[7];
        float* dst = out + (size_t)row * OUT_DIM + sl * 8;
        *reinterpret_cast<float4*>(dst) = o0;
        *reinterpret_cast<float4*>(dst + 4) = o1;
    }
}

// ---------------- launch ----------------
extern "C" void kernel_launch(void* const* d_in, const int* in_sizes, int n_in,
                              void* d_out, int out_size, void* d_ws, size_t ws_size,
                              hipStream_t stream) {
    const float* X    = (const float*)d_in[0];
    const float* W    = (const float*)d_in[1];
    const float* attw = (const float*)d_in[2];
    const int*   rp   = (const int*)d_in[3];
    const int*   ci   = (const int*)d_in[4];
    float* out = (float*)d_out;

    __bf16* XP = (__bf16*)d_ws;
    __bf16* Wt = (__bf16*)((char*)d_ws + (size_t)N_NODES * OUT_DIM * 2);

    prep_w_kernel<<<OUT_DIM, IN_DIM, 0, stream>>>(W, Wt);
    // 100000 rows = 3125 wave-chunks of 32 rows; 4 waves/block -> 782 blocks
    gemm_kernel<<<(3125 + 3) / 4, 256, 0, stream>>>(X, Wt, XP);
    gat_edge_kernel<<<N_NODES / 4, 256, 0, stream>>>(XP, rp, ci, attw, out);
}

// Round 4
// 97.425 us; speedup vs baseline: 1.1975x; 1.1975x over previous
//
#include <hip/hip_runtime.h>
#include <hip/hip_bf16.h>
#include <stdint.h>

#define N_NODES 100000
#define IN_DIM 256
#define OUT_DIM 128
#define DEG 16

typedef __bf16 bf16x8 __attribute__((ext_vector_type(8)));
typedef __bf16 bf16x4 __attribute__((ext_vector_type(4)));
typedef float f32x4 __attribute__((ext_vector_type(4)));

// ---------------- kernel A: Wt[j][k] = bf16(W[k][j]) ----------------
__global__ void prep_w_kernel(const float* __restrict__ W, __bf16* __restrict__ Wt) {
    const int j = blockIdx.x;   // 0..127 (output col)
    const int k = threadIdx.x;  // 0..255 (input dim)
    Wt[j * IN_DIM + k] = (__bf16)W[k * OUT_DIM + j];
}

// ---------------- kernel B: XP[m][n] = bf16( sum_k X[m][k] * W[k][n] ) ----------------
// Block = 256 thr (4 waves), tile = 64 rows x 128 cols, K = 256 in one shot.
// Staging: flat-linear float4 loads (each wave instruction = one contiguous 1KB
// row -> perfect coalescing), f32->bf16 in-reg, LDS row stride 264 (528B):
// ds_read_b128 slot = (lr+lg) mod 8 is uniform -> conflict-free 8-phase.
// Wave w computes cols [w*32, w*32+32): acc 4x2 f32x4, B direct from L2-resident Wt.
__global__ __launch_bounds__(256) void gemm_kernel(const float* __restrict__ X,
                                                   const __bf16* __restrict__ Wt,
                                                   __bf16* __restrict__ XP) {
    __shared__ __bf16 Alds[64][264];
    const int t = threadIdx.x;
    const int m0 = blockIdx.x * 64;

    // stage 64 rows x 256 cols f32 -> bf16 LDS; 16 iters x 256 thr x float4
    #pragma unroll
    for (int i = 0; i < 16; ++i) {
        const int flat = i * 256 + t;       // 0..4095
        const int row  = flat >> 6;         // 0..63
        const int col  = (flat & 63) * 4;   // 0..252
        int grow = m0 + row;
        if (grow >= N_NODES) grow = N_NODES - 1;   // clamp; stores are guarded
        float4 v = *reinterpret_cast<const float4*>(X + (size_t)grow * IN_DIM + col);
        bf16x4 b;
        b[0] = (__bf16)v.x; b[1] = (__bf16)v.y; b[2] = (__bf16)v.z; b[3] = (__bf16)v.w;
        *reinterpret_cast<bf16x4*>(&Alds[row][col]) = b;
    }
    __syncthreads();

    const int lane = t & 63;
    const int wave = t >> 6;
    const int n0 = wave * 32;
    const int lr = lane & 15;   // A row / B col / D col within fragment
    const int lg = lane >> 4;   // k-subgroup / D row-group

    f32x4 acc[4][2] = {};
    const __bf16* bp0 = Wt + (size_t)(n0 + lr) * IN_DIM + lg * 8;
    const __bf16* bp1 = bp0 + 16 * IN_DIM;

    #pragma unroll
    for (int ks = 0; ks < 8; ++ks) {
        const int ko = ks * 32 + lg * 8;
        bf16x8 b0 = *reinterpret_cast<const bf16x8*>(bp0 + ks * 32);
        bf16x8 b1 = *reinterpret_cast<const bf16x8*>(bp1 + ks * 32);
        bf16x8 a[4];
        #pragma unroll
        for (int mi = 0; mi < 4; ++mi)
            a[mi] = *reinterpret_cast<const bf16x8*>(&Alds[mi * 16 + lr][ko]);
        #pragma unroll
        for (int mi = 0; mi < 4; ++mi) {
            acc[mi][0] = __builtin_amdgcn_mfma_f32_16x16x32_bf16(a[mi], b0, acc[mi][0], 0, 0, 0);
            acc[mi][1] = __builtin_amdgcn_mfma_f32_16x16x32_bf16(a[mi], b1, acc[mi][1], 0, 0, 0);
        }
    }

    // C/D layout: col = lane&15, row = (lane>>4)*4 + r
    #pragma unroll
    for (int mi = 0; mi < 4; ++mi)
        #pragma unroll
        for (int ni = 0; ni < 2; ++ni)
            #pragma unroll
            for (int r = 0; r < 4; ++r) {
                const int row = m0 + mi * 16 + lg * 4 + r;
                if (row < N_NODES) {
                    const int col = n0 + ni * 16 + lr;
                    XP[(size_t)row * OUT_DIM + col] = (__bf16)acc[mi][ni][r];
                }
            }
}

// ---------------- kernel C: fused SDDMM + attention-weighted SpMM ----------------
// One wave per row. 4 groups of 16 lanes; group g owns edges [g*4, g*4+4);
// lane sl=lane&15 covers cols [sl*8, sl*8+8).
__global__ __launch_bounds__(256) void gat_edge_kernel(const __bf16* __restrict__ XP,
                                                       const int* __restrict__ rp,
                                                       const int* __restrict__ ci,
                                                       const float* __restrict__ attw,
                                                       float* __restrict__ out) {
    const int lane = threadIdx.x & 63;
    const int row = blockIdx.x * 4 + (threadIdx.x >> 6);
    const int g = lane >> 4;    // group 0..3
    const int sl = lane & 15;   // sub-lane: cols sl*8..sl*8+8

    float s = 0.f;
    #pragma unroll
    for (int h = 0; h < 8; ++h) s += attw[h];

    float x[8];
    {
        uint4 xv = *reinterpret_cast<const uint4*>(XP + (size_t)row * OUT_DIM + sl * 8);
        const uint32_t* xw = reinterpret_cast<const uint32_t*>(&xv);
        #pragma unroll
        for (int i = 0; i < 4; ++i) {
            x[2 * i]     = __uint_as_float(xw[i] << 16);
            x[2 * i + 1] = __uint_as_float(xw[i] & 0xffff0000u);
        }
    }

    const int4 cv = reinterpret_cast<const int4*>(ci + (size_t)row * DEG)[g];
    const int c[4] = {cv.x, cv.y, cv.z, cv.w};

    uint4 dvu[4];
    #pragma unroll
    for (int j = 0; j < 4; ++j)
        dvu[j] = *reinterpret_cast<const uint4*>(XP + (size_t)c[j] * OUT_DIM + sl * 8);

    float d[4][8];
    #pragma unroll
    for (int j = 0; j < 4; ++j) {
        const uint32_t* dw = reinterpret_cast<const uint32_t*>(&dvu[j]);
        #pragma unroll
        for (int i = 0; i < 4; ++i) {
            d[j][2 * i]     = __uint_as_float(dw[i] << 16);
            d[j][2 * i + 1] = __uint_as_float(dw[i] & 0xffff0000u);
        }
    }

    float p[4];
    #pragma unroll
    for (int j = 0; j < 4; ++j) {
        float t0 = 0.f;
        #pragma unroll
        for (int i = 0; i < 8; ++i) t0 += x[i] * d[j][i];
        p[j] = t0;
    }
    #pragma unroll
    for (int off = 1; off <= 8; off <<= 1) {
        #pragma unroll
        for (int j = 0; j < 4; ++j) p[j] += __shfl_xor(p[j], off);
    }

    float acc[8] = {};
    #pragma unroll
    for (int j = 0; j < 4; ++j) {
        const float att = p[j] * s;
        #pragma unroll
        for (int i = 0; i < 8; ++i) acc[i] += att * d[j][i];
    }

    #pragma unroll
    for (int off = 16; off <= 32; off <<= 1) {
        #pragma unroll
        for (int i = 0; i < 8; ++i) acc[i] += __shfl_xor(acc[i], off);
    }

    if (g == 0) {
        float4 o0, o1;
        o0.x = acc[0]; o0.y = acc[1]; o0.z = acc[2]; o0.w = acc[3];
        o1.x = acc[4]; o1.y = acc[5]; o1.z = acc[6]; o1.w = acc[7];
        float* dst = out + (size_t)row * OUT_DIM + sl * 8;
        *reinterpret_cast<float4*>(dst) = o0;
        *reinterpret_cast<float4*>(dst + 4) = o1;
    }
}

// ---------------- launch ----------------
extern "C" void kernel_launch(void* const* d_in, const int* in_sizes, int n_in,
                              void* d_out, int out_size, void* d_ws, size_t ws_size,
                              hipStream_t stream) {
    const float* X    = (const float*)d_in[0];
    const float* W    = (const float*)d_in[1];
    const float* attw = (const float*)d_in[2];
    const int*   rp   = (const int*)d_in[3];
    const int*   ci   = (const int*)d_in[4];
    float* out = (float*)d_out;

    __bf16* XP = (__bf16*)d_ws;
    __bf16* Wt = (__bf16*)((char*)d_ws + (size_t)N_NODES * OUT_DIM * 2);

    prep_w_kernel<<<OUT_DIM, IN_DIM, 0, stream>>>(W, Wt);
    gemm_kernel<<<(N_NODES + 63) / 64, 256, 0, stream>>>(X, Wt, XP);
    gat_edge_kernel<<<N_NODES / 4, 256, 0, stream>>>(XP, rp, ci, attw, out);
}